// Round 2
// baseline (1011.688 us; speedup 1.0000x reference)
//
#include <hip/hip_runtime.h>
#include <cstddef>

#define NN   16000          // nodes
#define NE   256000         // edges (without self loops)
#define EP   (NE + NN)      // 272000 with self loops
#define BG   32             // graphs
#define IN_F 768
#define HID  256
#define H1C  4
#define F1   (H1C * HID)    // 1024
#define OUTF 128
#define H2C  2
#define F2   (H2C * OUTF)   // 256

static __device__ __forceinline__ float lrelu02(float x) { return x > 0.f ? x : 0.2f * x; }
static __device__ __forceinline__ float eluf(float x)    { return x > 0.f ? x : expm1f(x); }

// ---------------- CSR build ----------------
__global__ void k_hist(const int* __restrict__ ei, int* __restrict__ deg) {
    int e = blockIdx.x * 256 + threadIdx.x;
    if (e >= EP) return;
    int d = (e < NE) ? ei[NE + e] : (e - NE);
    atomicAdd(&deg[d], 1);
}

__global__ void k_scan(const int* __restrict__ deg, int* __restrict__ off, int* __restrict__ cursor) {
    __shared__ int sums[256];
    int t = threadIdx.x;
    const int CH = (NN + 255) / 256;   // 63
    int base = t * CH;
    int s = 0;
    for (int i = 0; i < CH; ++i) { int idx = base + i; if (idx < NN) s += deg[idx]; }
    sums[t] = s;
    __syncthreads();
    for (int ofs = 1; ofs < 256; ofs <<= 1) {
        int v = 0;
        if (t >= ofs) v = sums[t - ofs];
        __syncthreads();
        sums[t] += v;
        __syncthreads();
    }
    int run = sums[t] - s;  // exclusive prefix of this chunk
    for (int i = 0; i < CH; ++i) {
        int idx = base + i;
        if (idx < NN) { off[idx] = run; cursor[idx] = run; run += deg[idx]; }
    }
    if (t == 255) off[NN] = run;
}

__global__ void k_scatter(const int* __restrict__ ei, int* __restrict__ cursor, int* __restrict__ csr_src) {
    int e = blockIdx.x * 256 + threadIdx.x;
    if (e >= EP) return;
    int s, d;
    if (e < NE) { s = ei[e]; d = ei[NE + e]; } else { s = d = e - NE; }
    int pos = atomicAdd(&cursor[d], 1);
    csr_src[pos] = s;
}

// ---------------- fp32 tiled GEMM: C[m,n] = sum_k A[m,k] * B[n,k] ----------------
template <int BM, int BN, int BK, int TM, int TN>
__global__ __launch_bounds__(256) void k_gemm_nt(const float* __restrict__ A,
                                                 const float* __restrict__ Bm,
                                                 float* __restrict__ C,
                                                 int M, int N, int K) {
    __shared__ __align__(16) float As[BK][BM + 4];
    __shared__ __align__(16) float Bs[BK][BN + 4];
    const int tid = threadIdx.x;
    const int tx = tid % (BN / TN);
    const int ty = tid / (BN / TN);
    const int m0 = blockIdx.y * BM, n0 = blockIdx.x * BN;
    float acc[TM][TN] = {};
    const int A_v4 = BM * BK / 4;
    const int B_v4 = BN * BK / 4;
    for (int k0 = 0; k0 < K; k0 += BK) {
        for (int l = tid; l < A_v4; l += 256) {
            int r = l / (BK / 4), c4 = (l % (BK / 4)) * 4;
            float4 v = *(const float4*)&A[(size_t)(m0 + r) * K + k0 + c4];
            As[c4 + 0][r] = v.x; As[c4 + 1][r] = v.y; As[c4 + 2][r] = v.z; As[c4 + 3][r] = v.w;
        }
        for (int l = tid; l < B_v4; l += 256) {
            int r = l / (BK / 4), c4 = (l % (BK / 4)) * 4;
            float4 v = *(const float4*)&Bm[(size_t)(n0 + r) * K + k0 + c4];
            Bs[c4 + 0][r] = v.x; Bs[c4 + 1][r] = v.y; Bs[c4 + 2][r] = v.z; Bs[c4 + 3][r] = v.w;
        }
        __syncthreads();
#pragma unroll
        for (int k = 0; k < BK; ++k) {
            float a[TM], b[TN];
#pragma unroll
            for (int i = 0; i < TM; i += 4) {
                float4 v = *(const float4*)&As[k][ty * TM + i];
                a[i] = v.x; a[i + 1] = v.y; a[i + 2] = v.z; a[i + 3] = v.w;
            }
#pragma unroll
            for (int j = 0; j < TN; j += 4) {
                float4 v = *(const float4*)&Bs[k][tx * TN + j];
                b[j] = v.x; b[j + 1] = v.y; b[j + 2] = v.z; b[j + 3] = v.w;
            }
#pragma unroll
            for (int i = 0; i < TM; ++i)
#pragma unroll
                for (int j = 0; j < TN; ++j) acc[i][j] += a[i] * b[j];
        }
        __syncthreads();
    }
    for (int i = 0; i < TM; ++i)
        for (int j = 0; j < TN; j += 4)
            *(float4*)&C[(size_t)(m0 + ty * TM + i) * N + n0 + tx * TN + j] =
                make_float4(acc[i][j], acc[i][j + 1], acc[i][j + 2], acc[i][j + 3]);
}

// ---------------- per-node attention logits ----------------
__global__ __launch_bounds__(256) void k_alpha1(const float* __restrict__ h,
                                                const float* __restrict__ a_s,
                                                const float* __restrict__ a_d,
                                                float* __restrict__ as_o,
                                                float* __restrict__ ad_o) {
    int n = blockIdx.x;
    int t = threadIdx.x;           // 256 threads, 4 floats each -> 1024 feats
    int head = t >> 6;             // one wave per head
    int f = t * 4;
    float4 hv = *(const float4*)&h[(size_t)n * F1 + f];
    float4 sv = *(const float4*)&a_s[f];
    float4 dv = *(const float4*)&a_d[f];
    float ps = hv.x * sv.x + hv.y * sv.y + hv.z * sv.z + hv.w * sv.w;
    float pd = hv.x * dv.x + hv.y * dv.y + hv.z * dv.z + hv.w * dv.w;
    for (int ofs = 32; ofs > 0; ofs >>= 1) {
        ps += __shfl_down(ps, ofs);
        pd += __shfl_down(pd, ofs);
    }
    if ((t & 63) == 0) { as_o[n * H1C + head] = ps; ad_o[n * H1C + head] = pd; }
}

__global__ __launch_bounds__(256) void k_alpha2(const float* __restrict__ h,
                                                const float* __restrict__ a_s,
                                                const float* __restrict__ a_d,
                                                float* __restrict__ as_o,
                                                float* __restrict__ ad_o) {
    int n = blockIdx.x * 4 + (threadIdx.x >> 6);
    int lane = threadIdx.x & 63;
    int f = lane * 4;              // 64 lanes * 4 = 256 feats
    float4 hv = *(const float4*)&h[(size_t)n * F2 + f];
    float4 sv = *(const float4*)&a_s[f];
    float4 dv = *(const float4*)&a_d[f];
    float ps = hv.x * sv.x + hv.y * sv.y + hv.z * sv.z + hv.w * sv.w;
    float pd = hv.x * dv.x + hv.y * dv.y + hv.z * dv.z + hv.w * dv.w;
    for (int ofs = 16; ofs > 0; ofs >>= 1) {
        ps += __shfl_down(ps, ofs, 32);
        pd += __shfl_down(pd, ofs, 32);
    }
    if ((lane & 31) == 0) {
        int head = lane >> 5;
        as_o[n * H2C + head] = ps;
        ad_o[n * H2C + head] = pd;
    }
}

// ---------------- layer-1 segment softmax + aggregate (+bias+elu) ----------------
__global__ __launch_bounds__(256) void k_gat1(const float* __restrict__ hbuf,
                                              const float* __restrict__ as1,
                                              const float* __restrict__ ad1,
                                              const int* __restrict__ off,
                                              const int* __restrict__ csr_src,
                                              const float* __restrict__ b1,
                                              float* __restrict__ h1) {
    __shared__ float smax[H1C], sden[H1C];
    __shared__ int s_edge[128];
    int d = blockIdx.x, t = threadIdx.x;
    int beg = off[d], end = off[d + 1];
    int head = t >> 6;
    if (t < 64) {
        float adv[H1C], mx[H1C], sm[H1C];
#pragma unroll
        for (int h = 0; h < H1C; ++h) { adv[h] = ad1[d * H1C + h]; mx[h] = -1e30f; }
        for (int j = beg + t; j < end; j += 64) {
            int s = csr_src[j];
#pragma unroll
            for (int h = 0; h < H1C; ++h) {
                float e = lrelu02(as1[s * H1C + h] + adv[h]);
                mx[h] = fmaxf(mx[h], e);
            }
        }
#pragma unroll
        for (int h = 0; h < H1C; ++h) {
            for (int ofs = 32; ofs > 0; ofs >>= 1) mx[h] = fmaxf(mx[h], __shfl_down(mx[h], ofs));
            mx[h] = __shfl(mx[h], 0);
            sm[h] = 0.f;
        }
        for (int j = beg + t; j < end; j += 64) {
            int s = csr_src[j];
#pragma unroll
            for (int h = 0; h < H1C; ++h) {
                float e = lrelu02(as1[s * H1C + h] + adv[h]);
                sm[h] += expf(e - mx[h]);
            }
        }
#pragma unroll
        for (int h = 0; h < H1C; ++h)
            for (int ofs = 32; ofs > 0; ofs >>= 1) sm[h] += __shfl_down(sm[h], ofs);
        if (t == 0) {
#pragma unroll
            for (int h = 0; h < H1C; ++h) { smax[h] = mx[h]; sden[h] = 1.f / (sm[h] + 1e-16f); }
        }
    }
    __syncthreads();
    float mh = smax[head], rd = sden[head];
    float advh = ad1[d * H1C + head];
    float4 acc = make_float4(0.f, 0.f, 0.f, 0.f);
    int fo = t * 4;
    for (int cbeg = beg; cbeg < end; cbeg += 128) {
        int cnt = end - cbeg; if (cnt > 128) cnt = 128;
        __syncthreads();
        if (t < cnt) s_edge[t] = csr_src[cbeg + t];
        __syncthreads();
        for (int jj = 0; jj < cnt; ++jj) {
            int s = s_edge[jj];
            float e = lrelu02(as1[s * H1C + head] + advh);
            float w = expf(e - mh) * rd;
            float4 hv = *(const float4*)&hbuf[(size_t)s * F1 + fo];
            acc.x += w * hv.x; acc.y += w * hv.y; acc.z += w * hv.z; acc.w += w * hv.w;
        }
    }
    float4 bb = *(const float4*)&b1[fo];
    float4 o;
    o.x = eluf(acc.x + bb.x);
    o.y = eluf(acc.y + bb.y);
    o.z = eluf(acc.z + bb.z);
    o.w = eluf(acc.w + bb.w);
    *(float4*)&h1[(size_t)d * F1 + fo] = o;
}

// ---------------- layer-2 softmax + aggregate + head-mean + bias + elu + pool ----------------
__global__ __launch_bounds__(256) void k_gat2(const float* __restrict__ h2l,
                                              const float* __restrict__ as2,
                                              const float* __restrict__ ad2,
                                              const int* __restrict__ off,
                                              const int* __restrict__ csr_src,
                                              const float* __restrict__ b2,
                                              const int* __restrict__ batch,
                                              float* __restrict__ out_h2,
                                              float* __restrict__ pooled,
                                              float* __restrict__ cnt) {
    __shared__ float smax[H2C], sden[H2C];
    __shared__ float tmp[F2];
    __shared__ int s_edge[128];
    int d = blockIdx.x, t = threadIdx.x;
    int beg = off[d], end = off[d + 1];
    int head = t >> 7;
    if (t < 64) {
        float adv0 = ad2[d * 2], adv1 = ad2[d * 2 + 1];
        float m0 = -1e30f, m1 = -1e30f, s0 = 0.f, s1 = 0.f;
        for (int j = beg + t; j < end; j += 64) {
            int s = csr_src[j];
            m0 = fmaxf(m0, lrelu02(as2[s * 2] + adv0));
            m1 = fmaxf(m1, lrelu02(as2[s * 2 + 1] + adv1));
        }
        for (int ofs = 32; ofs > 0; ofs >>= 1) {
            m0 = fmaxf(m0, __shfl_down(m0, ofs));
            m1 = fmaxf(m1, __shfl_down(m1, ofs));
        }
        m0 = __shfl(m0, 0); m1 = __shfl(m1, 0);
        for (int j = beg + t; j < end; j += 64) {
            int s = csr_src[j];
            s0 += expf(lrelu02(as2[s * 2] + adv0) - m0);
            s1 += expf(lrelu02(as2[s * 2 + 1] + adv1) - m1);
        }
        for (int ofs = 32; ofs > 0; ofs >>= 1) {
            s0 += __shfl_down(s0, ofs);
            s1 += __shfl_down(s1, ofs);
        }
        if (t == 0) {
            smax[0] = m0; smax[1] = m1;
            sden[0] = 1.f / (s0 + 1e-16f); sden[1] = 1.f / (s1 + 1e-16f);
        }
    }
    __syncthreads();
    float mh = smax[head], rd = sden[head];
    float advh = ad2[d * 2 + head];
    float acc = 0.f;
    for (int cbeg = beg; cbeg < end; cbeg += 128) {
        int c = end - cbeg; if (c > 128) c = 128;
        __syncthreads();
        if (t < c) s_edge[t] = csr_src[cbeg + t];
        __syncthreads();
        for (int jj = 0; jj < c; ++jj) {
            int s = s_edge[jj];
            float e = lrelu02(as2[s * 2 + head] + advh);
            float w = expf(e - mh) * rd;
            acc += w * h2l[(size_t)s * F2 + t];
        }
    }
    tmp[t] = acc;
    __syncthreads();
    if (t < 128) {
        float v = eluf(0.5f * (tmp[t] + tmp[t + 128]) + b2[t]);
        out_h2[(size_t)d * OUTF + t] = v;
        int b = batch[d];
        atomicAdd(&pooled[b * OUTF + t], v);
        if (t == 0) atomicAdd(&cnt[b], 1.0f);
    }
}

// ---------------- projection + LayerNorm ----------------
__global__ __launch_bounds__(256) void k_proj_ln(const float* __restrict__ pooled,
                                                 const float* __restrict__ cnt,
                                                 const float* __restrict__ pW,
                                                 const float* __restrict__ pb,
                                                 const float* __restrict__ g,
                                                 const float* __restrict__ be,
                                                 float* __restrict__ out) {
    __shared__ float ph[OUTF];
    __shared__ float zb[768];
    __shared__ float red[256];
    __shared__ float s_mu, s_rstd;
    int b = blockIdx.x, t = threadIdx.x;
    if (t < OUTF) {
        float c = cnt[b];
        c = c < 1.f ? 1.f : c;
        ph[t] = pooled[b * OUTF + t] / c;
    }
    __syncthreads();
    for (int r = 0; r < 3; ++r) {
        int j = t + 256 * r;
        float acc = pb[j];
        for (int k = 0; k < OUTF; k += 4) {
            float4 w = *(const float4*)&pW[(size_t)j * OUTF + k];
            acc += w.x * ph[k] + w.y * ph[k + 1] + w.z * ph[k + 2] + w.w * ph[k + 3];
        }
        zb[j] = acc;
    }
    __syncthreads();
    float s = zb[t] + zb[t + 256] + zb[t + 512];
    red[t] = s;
    __syncthreads();
    for (int ofs = 128; ofs > 0; ofs >>= 1) {
        if (t < ofs) red[t] += red[t + ofs];
        __syncthreads();
    }
    if (t == 0) s_mu = red[0] / 768.f;
    __syncthreads();
    float mu = s_mu;
    float d0 = zb[t] - mu, d1 = zb[t + 256] - mu, d2 = zb[t + 512] - mu;
    red[t] = d0 * d0 + d1 * d1 + d2 * d2;
    __syncthreads();
    for (int ofs = 128; ofs > 0; ofs >>= 1) {
        if (t < ofs) red[t] += red[t + ofs];
        __syncthreads();
    }
    if (t == 0) s_rstd = rsqrtf(red[0] / 768.f + 1e-5f);
    __syncthreads();
    float rstd = s_rstd;
    for (int r = 0; r < 3; ++r) {
        int j = t + 256 * r;
        out[(size_t)b * 768 + j] = (zb[j] - mu) * rstd * g[j] + be[j];
    }
}

extern "C" void kernel_launch(void* const* d_in, const int* in_sizes, int n_in,
                              void* d_out, int out_size, void* d_ws, size_t ws_size,
                              hipStream_t stream) {
    const float* x    = (const float*)d_in[0];
    const int*   ei   = (const int*)d_in[1];
    const int*   batch= (const int*)d_in[2];
    const float* W1   = (const float*)d_in[3];
    const float* a1s  = (const float*)d_in[4];
    const float* a1d  = (const float*)d_in[5];
    const float* b1   = (const float*)d_in[6];
    const float* W2   = (const float*)d_in[7];
    const float* a2s  = (const float*)d_in[8];
    const float* a2d  = (const float*)d_in[9];
    const float* b2   = (const float*)d_in[10];
    const float* pW   = (const float*)d_in[11];
    const float* pb   = (const float*)d_in[12];
    const float* lng  = (const float*)d_in[13];
    const float* lnb  = (const float*)d_in[14];

    float* out_ge = (float*)d_out;                 // (32, 768)
    float* out_h2 = (float*)d_out + BG * 768;      // (16000, 128)

    char* w = (char*)d_ws;
    float* hbuf = (float*)w;  w += (size_t)NN * F1 * 4;
    float* h1   = (float*)w;  w += (size_t)NN * F1 * 4;
    float* h2l  = (float*)w;  w += (size_t)NN * F2 * 4;
    float* as1  = (float*)w;  w += (size_t)NN * H1C * 4;
    float* ad1  = (float*)w;  w += (size_t)NN * H1C * 4;
    float* as2  = (float*)w;  w += (size_t)NN * H2C * 4;
    float* ad2  = (float*)w;  w += (size_t)NN * H2C * 4;
    int* deg    = (int*)w;    w += (size_t)NN * 4;
    int* off    = (int*)w;    w += (size_t)(NN + 4) * 4;
    int* cursor = (int*)w;    w += (size_t)NN * 4;
    int* csr    = (int*)w;    w += (size_t)EP * 4;
    float* pooled = (float*)w; w += (size_t)BG * OUTF * 4;
    float* cnt  = (float*)w;  w += (size_t)BG * 4;

    hipMemsetAsync(deg, 0, NN * 4, stream);
    hipMemsetAsync(pooled, 0, (BG * OUTF + BG) * 4, stream);

    k_hist<<<(EP + 255) / 256, 256, 0, stream>>>(ei, deg);
    k_scan<<<1, 256, 0, stream>>>(deg, off, cursor);
    k_scatter<<<(EP + 255) / 256, 256, 0, stream>>>(ei, cursor, csr);

    // GEMM1: hbuf = x @ W1^T   (16000x768 @ 768x1024)
    k_gemm_nt<128, 128, 16, 8, 8><<<dim3(F1 / 128, NN / 128), 256, 0, stream>>>(x, W1, hbuf, NN, F1, IN_F);
    k_alpha1<<<NN, 256, 0, stream>>>(hbuf, a1s, a1d, as1, ad1);
    k_gat1<<<NN, 256, 0, stream>>>(hbuf, as1, ad1, off, csr, b1, h1);

    // GEMM2: h2l = h1 @ W2^T   (16000x1024 @ 1024x256)
    k_gemm_nt<128, 64, 16, 8, 4><<<dim3(F2 / 64, NN / 128), 256, 0, stream>>>(h1, W2, h2l, NN, F2, F1);
    k_alpha2<<<NN / 4, 256, 0, stream>>>(h2l, a2s, a2d, as2, ad2);
    k_gat2<<<NN, 256, 0, stream>>>(h2l, as2, ad2, off, csr, b2, batch, out_h2, pooled, cnt);

    k_proj_ln<<<BG, 256, 0, stream>>>(pooled, cnt, pW, pb, lng, lnb, out_ge);
}

// Round 3
// 626.178 us; speedup vs baseline: 1.6157x; 1.6157x over previous
//
#include <hip/hip_runtime.h>
#include <cstddef>

#define NN   16000          // nodes
#define NE   256000         // edges (without self loops)
#define EP   (NE + NN)      // 272000 with self loops
#define BG   32             // graphs
#define IN_F 768
#define HID  256
#define H1C  4
#define F1   (H1C * HID)    // 1024
#define OUTF 128
#define H2C  2
#define F2   (H2C * OUTF)   // 256

typedef __bf16 bf16x8 __attribute__((ext_vector_type(8)));
typedef float  f32x4  __attribute__((ext_vector_type(4)));

static __device__ __forceinline__ float lrelu02(float x) { return x > 0.f ? x : 0.2f * x; }
static __device__ __forceinline__ float eluf(float x)    { return x > 0.f ? x : expm1f(x); }
static __device__ __forceinline__ unsigned short rne_bf16(float f) {
    unsigned u = __float_as_uint(f);
    return (unsigned short)((u + 0x7fffu + ((u >> 16) & 1u)) >> 16);
}

#define GLDS16(gp, lp) __builtin_amdgcn_global_load_lds(                         \
    (const __attribute__((address_space(1))) void*)(gp),                          \
    (__attribute__((address_space(3))) void*)(lp), 16, 0, 0)

// ---------------- fp32 -> bf16 convert ----------------
__global__ __launch_bounds__(256) void k_f2b(const float* __restrict__ in,
                                             unsigned short* __restrict__ out, int n) {
    int i = (blockIdx.x * 256 + threadIdx.x) * 4;
    if (i >= n) return;
    float4 v = *(const float4*)&in[i];
    ushort4 o;
    o.x = rne_bf16(v.x); o.y = rne_bf16(v.y); o.z = rne_bf16(v.z); o.w = rne_bf16(v.w);
    *(ushort4*)&out[i] = o;
}

// ---------------- CSR build ----------------
__global__ void k_hist(const int* __restrict__ ei, int* __restrict__ deg) {
    int e = blockIdx.x * 256 + threadIdx.x;
    if (e >= EP) return;
    int d = (e < NE) ? ei[NE + e] : (e - NE);
    atomicAdd(&deg[d], 1);
}

__global__ void k_scan(const int* __restrict__ deg, int* __restrict__ off, int* __restrict__ cursor) {
    __shared__ int sums[256];
    int t = threadIdx.x;
    const int CH = (NN + 255) / 256;
    int base = t * CH;
    int s = 0;
    for (int i = 0; i < CH; ++i) { int idx = base + i; if (idx < NN) s += deg[idx]; }
    sums[t] = s;
    __syncthreads();
    for (int ofs = 1; ofs < 256; ofs <<= 1) {
        int v = 0;
        if (t >= ofs) v = sums[t - ofs];
        __syncthreads();
        sums[t] += v;
        __syncthreads();
    }
    int run = sums[t] - s;
    for (int i = 0; i < CH; ++i) {
        int idx = base + i;
        if (idx < NN) { off[idx] = run; cursor[idx] = run; run += deg[idx]; }
    }
    if (t == 255) off[NN] = run;
}

__global__ void k_scatter(const int* __restrict__ ei, int* __restrict__ cursor, int* __restrict__ csr_src) {
    int e = blockIdx.x * 256 + threadIdx.x;
    if (e >= EP) return;
    int s, d;
    if (e < NE) { s = ei[e]; d = ei[NE + e]; } else { s = d = e - NE; }
    int pos = atomicAdd(&cursor[d], 1);
    csr_src[pos] = s;
}

// ---------------- bf16 MFMA GEMM: C[m,n] = sum_k A[m,k] * B[n,k], fp32 out ----------------
// 128x128 tile, BK=32, 4 waves each computing 64x64 via 4x4 of 16x16x32 mfma.
__global__ __launch_bounds__(256) void k_mfma_nt(const unsigned short* __restrict__ A,
                                                 const unsigned short* __restrict__ B,
                                                 float* __restrict__ C,
                                                 int N, int K) {
    __shared__ __align__(16) unsigned short As[128 * 32];
    __shared__ __align__(16) unsigned short Bs[128 * 32];
    const int t = threadIdx.x;
    const int w = t >> 6, lane = t & 63;
    const int m0 = blockIdx.y * 128, n0 = blockIdx.x * 128;
    const int wm = (w >> 1) * 64, wn = (w & 1) * 64;

    // staging: granule g = t + 256*j covers (row = g>>2, col8 = g&3) of a 128x32 tile
    const unsigned short* ga0 = A + (size_t)(m0 + (t >> 2)) * K + (t & 3) * 8;
    const unsigned short* ga1 = ga0 + (size_t)64 * K;
    const unsigned short* gb0 = B + (size_t)(n0 + (t >> 2)) * K + (t & 3) * 8;
    const unsigned short* gb1 = gb0 + (size_t)64 * K;
    unsigned short* lA0 = &As[(w * 64) * 8];
    unsigned short* lA1 = &As[(w * 64 + 256) * 8];
    unsigned short* lB0 = &Bs[(w * 64) * 8];
    unsigned short* lB1 = &Bs[(w * 64 + 256) * 8];

    f32x4 acc[4][4] = {};

    // fragment read ptrs: A[m=lane&15][k=(lane>>4)*8+j] -> granule row*4 + (lane>>4)
    const bf16x8* pa = (const bf16x8*)As + (wm + (lane & 15)) * 4 + (lane >> 4);
    const bf16x8* pb = (const bf16x8*)Bs + (wn + (lane & 15)) * 4 + (lane >> 4);

    for (int k0 = 0; k0 < K; k0 += 32) {
        GLDS16(ga0, lA0); GLDS16(ga1, lA1);
        GLDS16(gb0, lB0); GLDS16(gb1, lB1);
        ga0 += 32; ga1 += 32; gb0 += 32; gb1 += 32;
        __syncthreads();
        bf16x8 a0 = pa[0], a1 = pa[64], a2 = pa[128], a3 = pa[192];
        bf16x8 b0 = pb[0], b1 = pb[64], b2 = pb[128], b3 = pb[192];
        acc[0][0] = __builtin_amdgcn_mfma_f32_16x16x32_bf16(a0, b0, acc[0][0], 0, 0, 0);
        acc[0][1] = __builtin_amdgcn_mfma_f32_16x16x32_bf16(a0, b1, acc[0][1], 0, 0, 0);
        acc[0][2] = __builtin_amdgcn_mfma_f32_16x16x32_bf16(a0, b2, acc[0][2], 0, 0, 0);
        acc[0][3] = __builtin_amdgcn_mfma_f32_16x16x32_bf16(a0, b3, acc[0][3], 0, 0, 0);
        acc[1][0] = __builtin_amdgcn_mfma_f32_16x16x32_bf16(a1, b0, acc[1][0], 0, 0, 0);
        acc[1][1] = __builtin_amdgcn_mfma_f32_16x16x32_bf16(a1, b1, acc[1][1], 0, 0, 0);
        acc[1][2] = __builtin_amdgcn_mfma_f32_16x16x32_bf16(a1, b2, acc[1][2], 0, 0, 0);
        acc[1][3] = __builtin_amdgcn_mfma_f32_16x16x32_bf16(a1, b3, acc[1][3], 0, 0, 0);
        acc[2][0] = __builtin_amdgcn_mfma_f32_16x16x32_bf16(a2, b0, acc[2][0], 0, 0, 0);
        acc[2][1] = __builtin_amdgcn_mfma_f32_16x16x32_bf16(a2, b1, acc[2][1], 0, 0, 0);
        acc[2][2] = __builtin_amdgcn_mfma_f32_16x16x32_bf16(a2, b2, acc[2][2], 0, 0, 0);
        acc[2][3] = __builtin_amdgcn_mfma_f32_16x16x32_bf16(a2, b3, acc[2][3], 0, 0, 0);
        acc[3][0] = __builtin_amdgcn_mfma_f32_16x16x32_bf16(a3, b0, acc[3][0], 0, 0, 0);
        acc[3][1] = __builtin_amdgcn_mfma_f32_16x16x32_bf16(a3, b1, acc[3][1], 0, 0, 0);
        acc[3][2] = __builtin_amdgcn_mfma_f32_16x16x32_bf16(a3, b2, acc[3][2], 0, 0, 0);
        acc[3][3] = __builtin_amdgcn_mfma_f32_16x16x32_bf16(a3, b3, acc[3][3], 0, 0, 0);
        __syncthreads();
    }
    // C/D layout: col = lane&15, row = (lane>>4)*4 + reg  [measured m89/m91]
    const int ccol = n0 + wn + (lane & 15);
    const int crow = m0 + wm + (lane >> 4) * 4;
#pragma unroll
    for (int mi = 0; mi < 4; ++mi)
#pragma unroll
        for (int i = 0; i < 4; ++i) {
            float* cp = C + (size_t)(crow + mi * 16 + i) * N + ccol;
            cp[0]  = acc[mi][0][i];
            cp[16] = acc[mi][1][i];
            cp[32] = acc[mi][2][i];
            cp[48] = acc[mi][3][i];
        }
}

// ---------------- per-node attention logits ----------------
__global__ __launch_bounds__(256) void k_alpha1(const float* __restrict__ h,
                                                const float* __restrict__ a_s,
                                                const float* __restrict__ a_d,
                                                float* __restrict__ as_o,
                                                float* __restrict__ ad_o) {
    int n = blockIdx.x;
    int t = threadIdx.x;
    int head = t >> 6;
    int f = t * 4;
    float4 hv = *(const float4*)&h[(size_t)n * F1 + f];
    float4 sv = *(const float4*)&a_s[f];
    float4 dv = *(const float4*)&a_d[f];
    float ps = hv.x * sv.x + hv.y * sv.y + hv.z * sv.z + hv.w * sv.w;
    float pd = hv.x * dv.x + hv.y * dv.y + hv.z * dv.z + hv.w * dv.w;
    for (int ofs = 32; ofs > 0; ofs >>= 1) {
        ps += __shfl_down(ps, ofs);
        pd += __shfl_down(pd, ofs);
    }
    if ((t & 63) == 0) { as_o[n * H1C + head] = ps; ad_o[n * H1C + head] = pd; }
}

__global__ __launch_bounds__(256) void k_alpha2(const float* __restrict__ h,
                                                const float* __restrict__ a_s,
                                                const float* __restrict__ a_d,
                                                float* __restrict__ as_o,
                                                float* __restrict__ ad_o) {
    int n = blockIdx.x * 4 + (threadIdx.x >> 6);
    int lane = threadIdx.x & 63;
    int f = lane * 4;
    float4 hv = *(const float4*)&h[(size_t)n * F2 + f];
    float4 sv = *(const float4*)&a_s[f];
    float4 dv = *(const float4*)&a_d[f];
    float ps = hv.x * sv.x + hv.y * sv.y + hv.z * sv.z + hv.w * sv.w;
    float pd = hv.x * dv.x + hv.y * dv.y + hv.z * dv.z + hv.w * dv.w;
    for (int ofs = 16; ofs > 0; ofs >>= 1) {
        ps += __shfl_down(ps, ofs, 32);
        pd += __shfl_down(pd, ofs, 32);
    }
    if ((lane & 31) == 0) {
        int head = lane >> 5;
        as_o[n * H2C + head] = ps;
        ad_o[n * H2C + head] = pd;
    }
}

// ---------------- layer-1 segment softmax + aggregate (+bias+elu, bf16 out) ----------------
__global__ __launch_bounds__(256) void k_gat1(const float* __restrict__ hbuf,
                                              const float* __restrict__ as1,
                                              const float* __restrict__ ad1,
                                              const int* __restrict__ off,
                                              const int* __restrict__ csr_src,
                                              const float* __restrict__ b1,
                                              unsigned short* __restrict__ h1b) {
    __shared__ float smax[H1C], sden[H1C];
    __shared__ int s_edge[128];
    __shared__ float s_w[128 * H1C];
    int d = blockIdx.x, t = threadIdx.x;
    int beg = off[d], end = off[d + 1];
    int head = t >> 6;
    float4 adv4 = *(const float4*)&ad1[d * H1C];
    if (t < 64) {
        float mx[H1C], sm[H1C];
#pragma unroll
        for (int h = 0; h < H1C; ++h) mx[h] = -1e30f;
        for (int j = beg + t; j < end; j += 64) {
            int s = csr_src[j];
            float4 av = *(const float4*)&as1[s * H1C];
            mx[0] = fmaxf(mx[0], lrelu02(av.x + adv4.x));
            mx[1] = fmaxf(mx[1], lrelu02(av.y + adv4.y));
            mx[2] = fmaxf(mx[2], lrelu02(av.z + adv4.z));
            mx[3] = fmaxf(mx[3], lrelu02(av.w + adv4.w));
        }
#pragma unroll
        for (int h = 0; h < H1C; ++h) {
            for (int ofs = 32; ofs > 0; ofs >>= 1) mx[h] = fmaxf(mx[h], __shfl_down(mx[h], ofs));
            mx[h] = __shfl(mx[h], 0);
            sm[h] = 0.f;
        }
        for (int j = beg + t; j < end; j += 64) {
            int s = csr_src[j];
            float4 av = *(const float4*)&as1[s * H1C];
            sm[0] += expf(lrelu02(av.x + adv4.x) - mx[0]);
            sm[1] += expf(lrelu02(av.y + adv4.y) - mx[1]);
            sm[2] += expf(lrelu02(av.z + adv4.z) - mx[2]);
            sm[3] += expf(lrelu02(av.w + adv4.w) - mx[3]);
        }
#pragma unroll
        for (int h = 0; h < H1C; ++h)
            for (int ofs = 32; ofs > 0; ofs >>= 1) sm[h] += __shfl_down(sm[h], ofs);
        if (t == 0) {
#pragma unroll
            for (int h = 0; h < H1C; ++h) { smax[h] = mx[h]; sden[h] = 1.f / (sm[h] + 1e-16f); }
        }
    }
    __syncthreads();
    float4 acc0 = make_float4(0.f, 0.f, 0.f, 0.f);
    float4 acc1 = make_float4(0.f, 0.f, 0.f, 0.f);
    int fo = t * 4;
    for (int cbeg = beg; cbeg < end; cbeg += 128) {
        int cnt = end - cbeg; if (cnt > 128) cnt = 128;
        if (cbeg != beg) __syncthreads();
        if (t < cnt) {
            int s = csr_src[cbeg + t];
            s_edge[t] = s;
            float4 av = *(const float4*)&as1[s * H1C];
            s_w[t * 4 + 0] = expf(lrelu02(av.x + adv4.x) - smax[0]) * sden[0];
            s_w[t * 4 + 1] = expf(lrelu02(av.y + adv4.y) - smax[1]) * sden[1];
            s_w[t * 4 + 2] = expf(lrelu02(av.z + adv4.z) - smax[2]) * sden[2];
            s_w[t * 4 + 3] = expf(lrelu02(av.w + adv4.w) - smax[3]) * sden[3];
        }
        __syncthreads();
        int jj = 0;
        for (; jj + 1 < cnt; jj += 2) {
            int s0 = s_edge[jj], s1 = s_edge[jj + 1];
            float w0 = s_w[jj * 4 + head], w1 = s_w[(jj + 1) * 4 + head];
            float4 h0 = *(const float4*)&hbuf[(size_t)s0 * F1 + fo];
            float4 h1v = *(const float4*)&hbuf[(size_t)s1 * F1 + fo];
            acc0.x += w0 * h0.x;  acc0.y += w0 * h0.y;  acc0.z += w0 * h0.z;  acc0.w += w0 * h0.w;
            acc1.x += w1 * h1v.x; acc1.y += w1 * h1v.y; acc1.z += w1 * h1v.z; acc1.w += w1 * h1v.w;
        }
        if (jj < cnt) {
            int s0 = s_edge[jj];
            float w0 = s_w[jj * 4 + head];
            float4 h0 = *(const float4*)&hbuf[(size_t)s0 * F1 + fo];
            acc0.x += w0 * h0.x; acc0.y += w0 * h0.y; acc0.z += w0 * h0.z; acc0.w += w0 * h0.w;
        }
    }
    float4 bb = *(const float4*)&b1[fo];
    ushort4 ob;
    ob.x = rne_bf16(eluf(acc0.x + acc1.x + bb.x));
    ob.y = rne_bf16(eluf(acc0.y + acc1.y + bb.y));
    ob.z = rne_bf16(eluf(acc0.z + acc1.z + bb.z));
    ob.w = rne_bf16(eluf(acc0.w + acc1.w + bb.w));
    *(ushort4*)&h1b[(size_t)d * F1 + fo] = ob;
}

// ---------------- layer-2 softmax + aggregate + head-mean + bias + elu + pool ----------------
__global__ __launch_bounds__(256) void k_gat2(const float* __restrict__ h2l,
                                              const float* __restrict__ as2,
                                              const float* __restrict__ ad2,
                                              const int* __restrict__ off,
                                              const int* __restrict__ csr_src,
                                              const float* __restrict__ b2,
                                              const int* __restrict__ batch,
                                              float* __restrict__ out_h2,
                                              float* __restrict__ pooled,
                                              float* __restrict__ cnt) {
    __shared__ float smax[H2C], sden[H2C];
    __shared__ float tmp[F2];
    __shared__ int s_edge[128];
    __shared__ float s_w[128 * H2C];
    int d = blockIdx.x, t = threadIdx.x;
    int beg = off[d], end = off[d + 1];
    int head = t >> 7;
    float adv0 = ad2[d * 2], adv1 = ad2[d * 2 + 1];
    if (t < 64) {
        float m0 = -1e30f, m1 = -1e30f, s0 = 0.f, s1 = 0.f;
        for (int j = beg + t; j < end; j += 64) {
            int s = csr_src[j];
            float2 av = *(const float2*)&as2[s * 2];
            m0 = fmaxf(m0, lrelu02(av.x + adv0));
            m1 = fmaxf(m1, lrelu02(av.y + adv1));
        }
        for (int ofs = 32; ofs > 0; ofs >>= 1) {
            m0 = fmaxf(m0, __shfl_down(m0, ofs));
            m1 = fmaxf(m1, __shfl_down(m1, ofs));
        }
        m0 = __shfl(m0, 0); m1 = __shfl(m1, 0);
        for (int j = beg + t; j < end; j += 64) {
            int s = csr_src[j];
            float2 av = *(const float2*)&as2[s * 2];
            s0 += expf(lrelu02(av.x + adv0) - m0);
            s1 += expf(lrelu02(av.y + adv1) - m1);
        }
        for (int ofs = 32; ofs > 0; ofs >>= 1) {
            s0 += __shfl_down(s0, ofs);
            s1 += __shfl_down(s1, ofs);
        }
        if (t == 0) {
            smax[0] = m0; smax[1] = m1;
            sden[0] = 1.f / (s0 + 1e-16f); sden[1] = 1.f / (s1 + 1e-16f);
        }
    }
    __syncthreads();
    float acc0 = 0.f, acc1 = 0.f;
    for (int cbeg = beg; cbeg < end; cbeg += 128) {
        int c = end - cbeg; if (c > 128) c = 128;
        if (cbeg != beg) __syncthreads();
        if (t < c) {
            int s = csr_src[cbeg + t];
            s_edge[t] = s;
            float2 av = *(const float2*)&as2[s * 2];
            s_w[t * 2 + 0] = expf(lrelu02(av.x + adv0) - smax[0]) * sden[0];
            s_w[t * 2 + 1] = expf(lrelu02(av.y + adv1) - smax[1]) * sden[1];
        }
        __syncthreads();
        int jj = 0;
        for (; jj + 1 < c; jj += 2) {
            int s0 = s_edge[jj], s1 = s_edge[jj + 1];
            float w0 = s_w[jj * 2 + head], w1 = s_w[(jj + 1) * 2 + head];
            acc0 += w0 * h2l[(size_t)s0 * F2 + t];
            acc1 += w1 * h2l[(size_t)s1 * F2 + t];
        }
        if (jj < c) {
            int s0 = s_edge[jj];
            acc0 += s_w[jj * 2 + head] * h2l[(size_t)s0 * F2 + t];
        }
    }
    tmp[t] = acc0 + acc1;
    __syncthreads();
    if (t < 128) {
        float v = eluf(0.5f * (tmp[t] + tmp[t + 128]) + b2[t]);
        out_h2[(size_t)d * OUTF + t] = v;
        int b = batch[d];
        atomicAdd(&pooled[b * OUTF + t], v);
        if (t == 0) atomicAdd(&cnt[b], 1.0f);
    }
}

// ---------------- projection + LayerNorm ----------------
__global__ __launch_bounds__(256) void k_proj_ln(const float* __restrict__ pooled,
                                                 const float* __restrict__ cnt,
                                                 const float* __restrict__ pW,
                                                 const float* __restrict__ pb,
                                                 const float* __restrict__ g,
                                                 const float* __restrict__ be,
                                                 float* __restrict__ out) {
    __shared__ float ph[OUTF];
    __shared__ float zb[768];
    __shared__ float red[256];
    __shared__ float s_mu, s_rstd;
    int b = blockIdx.x, t = threadIdx.x;
    if (t < OUTF) {
        float c = cnt[b];
        c = c < 1.f ? 1.f : c;
        ph[t] = pooled[b * OUTF + t] / c;
    }
    __syncthreads();
    for (int r = 0; r < 3; ++r) {
        int j = t + 256 * r;
        float acc = pb[j];
        for (int k = 0; k < OUTF; k += 4) {
            float4 w = *(const float4*)&pW[(size_t)j * OUTF + k];
            acc += w.x * ph[k] + w.y * ph[k + 1] + w.z * ph[k + 2] + w.w * ph[k + 3];
        }
        zb[j] = acc;
    }
    __syncthreads();
    float s = zb[t] + zb[t + 256] + zb[t + 512];
    red[t] = s;
    __syncthreads();
    for (int ofs = 128; ofs > 0; ofs >>= 1) {
        if (t < ofs) red[t] += red[t + ofs];
        __syncthreads();
    }
    if (t == 0) s_mu = red[0] / 768.f;
    __syncthreads();
    float mu = s_mu;
    float d0 = zb[t] - mu, d1 = zb[t + 256] - mu, d2 = zb[t + 512] - mu;
    red[t] = d0 * d0 + d1 * d1 + d2 * d2;
    __syncthreads();
    for (int ofs = 128; ofs > 0; ofs >>= 1) {
        if (t < ofs) red[t] += red[t + ofs];
        __syncthreads();
    }
    if (t == 0) s_rstd = rsqrtf(red[0] / 768.f + 1e-5f);
    __syncthreads();
    float rstd = s_rstd;
    for (int r = 0; r < 3; ++r) {
        int j = t + 256 * r;
        out[(size_t)b * 768 + j] = (zb[j] - mu) * rstd * g[j] + be[j];
    }
}

extern "C" void kernel_launch(void* const* d_in, const int* in_sizes, int n_in,
                              void* d_out, int out_size, void* d_ws, size_t ws_size,
                              hipStream_t stream) {
    const float* x    = (const float*)d_in[0];
    const int*   ei   = (const int*)d_in[1];
    const int*   batch= (const int*)d_in[2];
    const float* W1   = (const float*)d_in[3];
    const float* a1s  = (const float*)d_in[4];
    const float* a1d  = (const float*)d_in[5];
    const float* b1   = (const float*)d_in[6];
    const float* W2   = (const float*)d_in[7];
    const float* a2s  = (const float*)d_in[8];
    const float* a2d  = (const float*)d_in[9];
    const float* b2   = (const float*)d_in[10];
    const float* pW   = (const float*)d_in[11];
    const float* pb   = (const float*)d_in[12];
    const float* lng  = (const float*)d_in[13];
    const float* lnb  = (const float*)d_in[14];

    float* out_ge = (float*)d_out;                 // (32, 768)
    float* out_h2 = (float*)d_out + BG * 768;      // (16000, 128)

    char* w = (char*)d_ws;
    float* hbuf = (float*)w;          w += (size_t)NN * F1 * 4;     // GEMM1 out fp32
    float* h2l  = (float*)w;          w += (size_t)NN * F2 * 4;     // GEMM2 out fp32
    unsigned short* xb  = (unsigned short*)w;  w += (size_t)NN * IN_F * 2;
    unsigned short* h1b = (unsigned short*)w;  w += (size_t)NN * F1 * 2;
    unsigned short* W1b = (unsigned short*)w;  w += (size_t)F1 * IN_F * 2;
    unsigned short* W2b = (unsigned short*)w;  w += (size_t)F2 * F1 * 2;
    float* as1  = (float*)w;  w += (size_t)NN * H1C * 4;
    float* ad1  = (float*)w;  w += (size_t)NN * H1C * 4;
    float* as2  = (float*)w;  w += (size_t)NN * H2C * 4;
    float* ad2  = (float*)w;  w += (size_t)NN * H2C * 4;
    int* deg    = (int*)w;    w += (size_t)NN * 4;
    int* off    = (int*)w;    w += (size_t)(NN + 4) * 4;
    int* cursor = (int*)w;    w += (size_t)NN * 4;
    int* csr    = (int*)w;    w += (size_t)EP * 4;
    float* pooled = (float*)w; w += (size_t)BG * OUTF * 4;
    float* cnt  = (float*)w;  w += (size_t)BG * 4;

    hipMemsetAsync(deg, 0, NN * 4, stream);
    hipMemsetAsync(pooled, 0, (BG * OUTF + BG) * 4, stream);

    // converts (independent of CSR build)
    k_f2b<<<(NN * IN_F) / 1024, 256, 0, stream>>>(x, xb, NN * IN_F);
    k_f2b<<<(F1 * IN_F) / 1024, 256, 0, stream>>>(W1, W1b, F1 * IN_F);
    k_f2b<<<(F2 * F1) / 1024, 256, 0, stream>>>(W2, W2b, F2 * F1);

    k_hist<<<(EP + 255) / 256, 256, 0, stream>>>(ei, deg);
    k_scan<<<1, 256, 0, stream>>>(deg, off, cursor);
    k_scatter<<<(EP + 255) / 256, 256, 0, stream>>>(ei, cursor, csr);

    // GEMM1: hbuf = x @ W1^T   (16000x768 @ 768x1024) bf16 MFMA
    k_mfma_nt<<<dim3(F1 / 128, NN / 128), 256, 0, stream>>>(xb, W1b, hbuf, F1, IN_F);
    k_alpha1<<<NN, 256, 0, stream>>>(hbuf, a1s, a1d, as1, ad1);
    k_gat1<<<NN, 256, 0, stream>>>(hbuf, as1, ad1, off, csr, b1, h1b);

    // GEMM2: h2l = h1 @ W2^T   (16000x1024 @ 1024x256) bf16 MFMA
    k_mfma_nt<<<dim3(F2 / 128, NN / 128), 256, 0, stream>>>(h1b, W2b, h2l, F2, F1);
    k_alpha2<<<NN / 4, 256, 0, stream>>>(h2l, a2s, a2d, as2, ad2);
    k_gat2<<<NN, 256, 0, stream>>>(h2l, as2, ad2, off, csr, b2, batch, out_h2, pooled, cnt);

    k_proj_ln<<<BG, 256, 0, stream>>>(pooled, cnt, pW, pb, lng, lnb, out_ge);
}